// Round 10
// baseline (786.557 us; speedup 1.0000x reference)
//
#include <hip/hip_runtime.h>
#include <cstdint>
#include <cstddef>

#pragma clang fp contract(off)

typedef unsigned long long u64;

#define NB 32
#define NA 9
#define NH 128
#define NW 128
#define HW (NH*NW)            // 16384
#define NANCH (NA*HW)         // 147456
#define PRE_N 6000
#define POST_N 300
#define CAND_CAP 8192
#define NMS_T 0.7f
#define GX_GATHER 24          // blocks per image in k_gather
#define NBOX 6144             // boxes carried into NMS
#define CH 512                // NMS chunk size

// Base anchor widths/heights (generate_anchors(16,[.5,1,2],[8,16,32])).
__constant__ float c_wa[9] = {184.f,368.f,736.f,128.f,256.f,512.f,88.f,176.f,352.f};
__constant__ float c_ha[9] = {96.f,192.f,384.f,128.f,256.f,512.f,176.f,352.f,704.f};

__device__ __forceinline__ float4 decode_clip(int a, int h, int w,
    float dx, float dy, float dlw, float dlh, float imh, float imw) {
  float wa = c_wa[a], ha = c_ha[a];
  float cx = (float)w * 16.0f + 8.0f;
  float cy = (float)h * 16.0f + 8.0f;
  float pcx = dx * wa + cx;
  float pcy = dy * ha + cy;
  float pw = expf(dlw) * wa;
  float ph = expf(dlh) * ha;
  float x1 = pcx - 0.5f * pw;
  float y1 = pcy - 0.5f * ph;
  float x2 = pcx + 0.5f * pw;
  float y2 = pcy + 0.5f * ph;
  float4 r;
  r.x = fminf(fmaxf(x1, 0.0f), imw - 1.0f);
  r.y = fminf(fmaxf(y1, 0.0f), imh - 1.0f);
  r.z = fminf(fmaxf(x2, 0.0f), imw - 1.0f);
  r.w = fminf(fmaxf(y2, 0.0f), imh - 1.0f);
  return r;
}

__device__ __forceinline__ unsigned score_key(float sc, float bw, float bh, float msz) {
  unsigned bits = __float_as_uint(sc);
  unsigned key = (bits & 0x80000000u) ? ~bits : (bits | 0x80000000u);
  if (!(bw >= msz && bh >= msz)) key = 0u;   // filtered == score NEG_INF
  return key;
}

__device__ __forceinline__ bool sup_test4(float4 v, float ar, float4 p, float pa) {
  float xx1 = fmaxf(p.x, v.x), yy1 = fmaxf(p.y, v.y);
  float xx2 = fminf(p.z, v.z), yy2 = fminf(p.w, v.w);
  float iw = fmaxf(xx2 - xx1 + 1.0f, 0.0f);
  float ih = fmaxf(yy2 - yy1 + 1.0f, 0.0f);
  float inter = iw * ih;
  float iou = inter / fmaxf(pa + ar - inter, 1e-6f);
  return iou > NMS_T;
}

// ---- hybrid bitonic sort helpers (1024 threads, 8 elems/thread) ------------
__device__ __forceinline__ u64 shfl_xor_u64(u64 x, int m) {
  int lo = __shfl_xor((int)(unsigned)x, m, 64);
  int hi = __shfl_xor((int)(unsigned)(x >> 32), m, 64);
  return ((u64)(unsigned)hi << 32) | (unsigned)lo;
}

__device__ __forceinline__ void reg_step(u64 v[8], int t, int k, int j) {
  #pragma unroll
  for (int r = 0; r < 8; ++r) {
    if ((r & j) == 0) {
      int e = (t << 3) + r;
      bool up = ((e & k) == 0);          // up-region = descending
      u64 x = v[r], y = v[r | j];
      u64 mx = x > y ? x : y, mn = x > y ? y : x;
      v[r]     = up ? mx : mn;
      v[r | j] = up ? mn : mx;
    }
  }
}

__device__ __forceinline__ void shfl_step(u64 v[8], int t, int k, int j) {
  int m = j >> 3;
  bool lower = ((t & m) == 0);
  #pragma unroll
  for (int r = 0; r < 8; ++r) {
    int e = (t << 3) + r;
    bool up = ((e & k) == 0);
    u64 pv = shfl_xor_u64(v[r], m);
    bool keepmax = (up == lower);
    u64 x = v[r];
    u64 mx = x > pv ? x : pv, mn = x > pv ? pv : x;
    v[r] = keepmax ? mx : mn;
  }
}

// j >= 512: cross-wave exchange via LDS, swizzled slot(e) = (e&7)*1024+(e>>3).
__device__ __forceinline__ void lds_step(u64* sm, u64 v[8], int t, int k, int j) {
  int m = j >> 3;
  __syncthreads();
  #pragma unroll
  for (int r = 0; r < 8; ++r) sm[(r << 10) | t] = v[r];
  __syncthreads();
  bool lower = ((t & m) == 0);
  bool up = (((t << 3) & k) == 0);
  bool keepmax = (up == lower);
  int pt = t ^ m;
  #pragma unroll
  for (int r = 0; r < 8; ++r) {
    u64 pv = sm[(r << 10) | pt];
    u64 x = v[r];
    u64 mx = x > pv ? x : pv, mn = x > pv ? pv : x;
    v[r] = keepmax ? mx : mn;
  }
}

// ---- inline radix-select helpers (256-thread blocks; r5-verified) ----------
__device__ void find_B(const unsigned* __restrict__ hb, unsigned* part,
                       unsigned* outB, unsigned* outCum) {
  int tid = threadIdx.x;
  unsigned s = 0;
  for (int i = 0; i < 16; ++i) s += hb[tid*16 + i];
  part[tid] = s;
  __syncthreads();
  for (int off = 1; off < 256; off <<= 1) {
    unsigned v = (tid + off < 256) ? part[tid + off] : 0u;
    __syncthreads();
    part[tid] += v;
    __syncthreads();
  }
  unsigned St = part[tid];
  unsigned Sn = (tid < 255) ? part[tid + 1] : 0u;
  if (St >= (unsigned)PRE_N && Sn < (unsigned)PRE_N) {
    unsigned cum = Sn, B = 0, cumAbove = Sn;
    for (int i = 15; i >= 0; --i) {
      unsigned v = hb[tid*16 + i];
      if (cum + v >= (unsigned)PRE_N) { B = (unsigned)(tid*16 + i); cumAbove = cum; break; }
      cum += v;
    }
    *outB = B; *outCum = cumAbove;
  }
  __syncthreads();
}

__device__ void find_thr(const unsigned* __restrict__ hb2, unsigned B, unsigned cum0,
                         unsigned* part, unsigned* outThr) {
  int tid = threadIdx.x;
  unsigned s = 0;
  for (int i = 0; i < 16; ++i) s += hb2[tid*16 + i];
  part[tid] = s;
  __syncthreads();
  for (int off = 1; off < 256; off <<= 1) {
    unsigned v = (tid + off < 256) ? part[tid + off] : 0u;
    __syncthreads();
    part[tid] += v;
    __syncthreads();
  }
  unsigned St = cum0 + part[tid];
  unsigned Sn = cum0 + ((tid < 255) ? part[tid + 1] : 0u);
  if (St >= (unsigned)PRE_N && Sn < (unsigned)PRE_N) {
    unsigned cum = Sn, t = 1u;
    for (int i = 15; i >= 0; --i) {
      unsigned v = hb2[tid*16 + i];
      if (cum + v >= (unsigned)PRE_N) {
        t = (B << 20) | ((unsigned)(tid*16 + i) << 8);
        break;
      }
      cum += v;
    }
    if (t == 0u) t = 1u;
    *outThr = t;
  }
  __syncthreads();
}

// K1: decode+filter -> order-preserving uint key per anchor, fused coarse
// histogram (key>>20, 4096 bins) aggregated in LDS, flushed per block.
__global__ __launch_bounds__(256) void k_keys(const float* __restrict__ cls,
    const float* __restrict__ dl, const float* __restrict__ info,
    unsigned* __restrict__ keys, unsigned* __restrict__ hist) {
  __shared__ unsigned hsh[4096];
  int tid = threadIdx.x;
  for (int i = tid; i < 4096; i += 256) hsh[i] = 0;
  int t = blockIdx.x * 256 + tid;            // 0..4095
  int b = blockIdx.y;
  int hw0 = t * 4;                           // 4 consecutive hw, same row
  int h = hw0 >> 7;
  const float* dlb  = dl  + (size_t)b * (4*NA*HW);
  const float* clsb = cls + (size_t)b * (2*NA*HW);
  float imh = info[b*3+0], imw = info[b*3+1];
  float msz = 16.0f * info[b*3+2];
  unsigned* kb = keys + (size_t)b * NANCH;
  __syncthreads();
  #pragma unroll
  for (int a = 0; a < 9; ++a) {
    float4 dx4 = *(const float4*)&dlb[(a*4+0)*HW + hw0];
    float4 dy4 = *(const float4*)&dlb[(a*4+1)*HW + hw0];
    float4 dw4 = *(const float4*)&dlb[(a*4+2)*HW + hw0];
    float4 dh4 = *(const float4*)&dlb[(a*4+3)*HW + hw0];
    float4 sc4 = *(const float4*)&clsb[(NA+a)*HW + hw0];
    uint4 out;
    {
      float4 bx = decode_clip(a, h, (hw0+0)&127, dx4.x, dy4.x, dw4.x, dh4.x, imh, imw);
      out.x = score_key(sc4.x, bx.z-bx.x+1.0f, bx.w-bx.y+1.0f, msz);
    }
    {
      float4 bx = decode_clip(a, h, (hw0+1)&127, dx4.y, dy4.y, dw4.y, dh4.y, imh, imw);
      out.y = score_key(sc4.y, bx.z-bx.x+1.0f, bx.w-bx.y+1.0f, msz);
    }
    {
      float4 bx = decode_clip(a, h, (hw0+2)&127, dx4.z, dy4.z, dw4.z, dh4.z, imh, imw);
      out.z = score_key(sc4.z, bx.z-bx.x+1.0f, bx.w-bx.y+1.0f, msz);
    }
    {
      float4 bx = decode_clip(a, h, (hw0+3)&127, dx4.w, dy4.w, dw4.w, dh4.w, imh, imw);
      out.w = score_key(sc4.w, bx.z-bx.x+1.0f, bx.w-bx.y+1.0f, msz);
    }
    *(uint4*)&kb[a*HW + hw0] = out;
    atomicAdd(&hsh[out.x >> 20], 1u);
    atomicAdd(&hsh[out.y >> 20], 1u);
    atomicAdd(&hsh[out.z >> 20], 1u);
    atomicAdd(&hsh[out.w >> 20], 1u);
  }
  __syncthreads();
  unsigned* gb = hist + ((size_t)b << 12);
  for (int i = tid; i < 4096; i += 256) {
    unsigned v = hsh[i];
    if (v) atomicAdd(&gb[i], v);
  }
}

// K2: refine histogram — bits[19:8] of keys whose top-12 == B (B inline from h1).
__global__ __launch_bounds__(256) void k_hist2(const unsigned* __restrict__ keys,
    const unsigned* __restrict__ hist1, unsigned* __restrict__ hist2) {
  __shared__ unsigned h[4096];
  __shared__ unsigned part[256];
  __shared__ unsigned sB, sCum;
  int b = blockIdx.y, tid = threadIdx.x;
  for (int i = tid; i < 4096; i += 256) h[i] = 0;
  __syncthreads();
  find_B(hist1 + ((size_t)b << 12), part, &sB, &sCum);
  unsigned B = sB;
  const unsigned* kb = keys + (size_t)b * NANCH;
  for (int i = blockIdx.x * 256 + tid; i < NANCH; i += gridDim.x * 256) {
    unsigned k = kb[i];
    if ((k >> 20) == B) atomicAdd(&h[(k >> 8) & 4095u], 1u);
  }
  __syncthreads();
  unsigned* gb = hist2 + ((size_t)b << 12);
  for (int i = tid; i < 4096; i += 256) { unsigned v = h[i]; if (v) atomicAdd(&gb[i], v); }
}

// K3: gather (key,[~oi:18|pos:13]) for key >= thr, AND decode the box into
// boxes[b][pos]. Tie-break preserved (~oi); pos lets the final kernel fetch
// the box without touching dl.
__global__ __launch_bounds__(256) void k_gather(const unsigned* __restrict__ keys,
    const unsigned* __restrict__ hist1, const unsigned* __restrict__ hist2,
    const float* __restrict__ dl, const float* __restrict__ info,
    unsigned* __restrict__ cnt, u64* __restrict__ cand,
    float4* __restrict__ boxes) {
  int b = blockIdx.y, tid = threadIdx.x;
  int lane = tid & 63, wv = tid >> 6;
  __shared__ unsigned part[256];
  __shared__ unsigned sB, sCum, sThr;
  __shared__ unsigned wcnt[4], woff[4], blkbase;
  if (tid == 0) sThr = 1u;
  __syncthreads();
  find_B(hist1 + ((size_t)b << 12), part, &sB, &sCum);
  find_thr(hist2 + ((size_t)b << 12), sB, sCum, part, &sThr);
  unsigned t_ = sThr;
  const unsigned* kb = keys + (size_t)b * NANCH;
  const float* dlb = dl + (size_t)b * (4*NA*HW);
  float imh = info[b*3+0], imw = info[b*3+1];
  u64* cb = cand + (size_t)b * CAND_CAP;
  float4* bxc = boxes + (size_t)b * CAND_CAP;
  unsigned* cp = cnt + (size_t)b * 64;
  const int PER_BLK = NANCH / GX_GATHER;      // 6144
  int base0 = blockIdx.x * PER_BLK;
  for (int it = 0; it < PER_BLK / 256; ++it) {
    int j = base0 + it * 256 + tid;
    unsigned key = kb[j];
    bool pass = key >= t_;
    u64 mask = __ballot(pass);
    if (lane == 0) wcnt[wv] = (unsigned)__popcll(mask);
    __syncthreads();
    if (tid == 0) {
      unsigned s0 = 0;
      for (int w = 0; w < 4; ++w) { woff[w] = s0; s0 += wcnt[w]; }
      blkbase = s0 ? atomicAdd(cp, s0) : 0u;
    }
    __syncthreads();
    if (pass) {
      unsigned pos = blkbase + woff[wv] + (unsigned)__popcll(mask & ((1ull << lane) - 1ull));
      if (pos < CAND_CAP) {
        int a = j >> 14, hw = j & (HW - 1);
        unsigned oi = (unsigned)(hw * 9 + a);
        unsigned noi = (~oi) & 0x3FFFFu;          // 18-bit inverted index
        cb[pos] = ((u64)key << 32) | ((u64)noi << 13) | (u64)pos;
        bxc[pos] = decode_clip(a, hw >> 7, hw & 127,
                               dlb[(a*4+0)*HW + hw], dlb[(a*4+1)*HW + hw],
                               dlb[(a*4+2)*HW + hw], dlb[(a*4+3)*HW + hw],
                               imh, imw);
      }
    }
    __syncthreads();
  }
}

// K4: hybrid-bitonic full sort + box gather + greedy NMS with FORWARD
// suppression (r9-verified, unchanged).
__global__ __launch_bounds__(1024) void k_final6(const u64* __restrict__ cand,
    const unsigned* __restrict__ cnt, const float4* __restrict__ boxes,
    float* __restrict__ out) {
  __shared__ float4 bx[NBOX];        // 96 KiB; first 64 KiB aliased as u64 sm[8192]
  __shared__ float4 cbox2[CH];       // compacted alive boxes (score order)
  __shared__ float  carea2[CH];
  __shared__ float4 kbox[POST_N];
  __shared__ float  karea[POST_N];
  __shared__ u64 sup[CH][9];         // padded row
  __shared__ u64 aliveM[8];
  __shared__ u64 kgW[8];
  __shared__ int s_nk;
  u64* sm = (u64*)bx;

  int b = blockIdx.x, tid = threadIdx.x;
  int lane = tid & 63, wv = tid >> 6;
  if (tid == 0) s_nk = 0;

  // ---- load 8 consecutive candidates into registers (masked by cnt) ----
  unsigned effcnt = cnt[b * 64];
  if (effcnt > CAND_CAP) effcnt = CAND_CAP;
  const u64* cb = cand + (size_t)b * CAND_CAP;
  int e0 = tid << 3;
  u64 v[8];
  #pragma unroll
  for (int r = 0; r < 8; ++r)
    v[r] = ((unsigned)(e0 + r) < effcnt) ? cb[e0 + r] : 0ull;

  // ---- full bitonic sort, descending ----
  for (int k = 2; k <= 8; k <<= 1)
    for (int j = k >> 1; j >= 1; j >>= 1) reg_step(v, tid, k, j);
  for (int k = 16; k <= CAND_CAP; k <<= 1) {
    int j = k >> 1;
    for (; j >= 512; j >>= 1) lds_step(sm, v, tid, k, j);
    for (; j >= 8;   j >>= 1) shfl_step(v, tid, k, j);
    for (; j >= 1;   j >>= 1) reg_step(v, tid, k, j);
  }
  __syncthreads();   // lds_step reads done before bx overwrites sm bytes

  // ---- fill bx by rank from the boxes array ----
  const float4* bxc = boxes + (size_t)b * CAND_CAP;
  #pragma unroll
  for (int r = 0; r < 8; ++r) {
    int rank = e0 + r;
    if (rank < NBOX) {
      u64 ck = (rank < PRE_N) ? v[r] : 0ull;
      float4 w = make_float4(0.f, 0.f, -1.f, -1.f);   // invalid: width 0
      if ((unsigned)(ck >> 32) != 0u)
        w = bxc[(unsigned)(ck & 0x1FFFu)];
      bx[rank] = w;
    }
  }
  __syncthreads();

  // ---- reload strided: thread t owns ranks t+1024*m (m static) ----
  float4 mybx[6];
  float  myar[6];
  int deadm = 0;
  #pragma unroll
  for (int m = 0; m < 6; ++m) {
    float4 w = bx[tid + (m << 10)];
    mybx[m] = w;
    float wid = w.z - w.x + 1.0f;
    myar[m] = wid * (w.w - w.y + 1.0f);
    if (!(wid > 0.0f)) deadm |= (1 << m);
  }

  // ---- greedy NMS, 12 chunks fully unrolled (chunk c=2m+par) ----
  float* ob = out + (size_t)b * (POST_N * 5);
  int c512 = tid & (CH - 1);
  int seg = tid >> 9;
  bool done = false;

  #pragma unroll
  for (int m = 0; m < 6; ++m) {
    #pragma unroll
    for (int par = 0; par < 2; ++par) {
      if (done) continue;
      int nk0 = s_nk;

      // 1. alive ballot straight from register flags (owner waves = 8)
      bool own = (tid >> 9) == par;
      int cc = tid - (par << 9);
      bool alive = own && !((deadm >> m) & 1);
      {
        u64 am = __ballot(alive);
        if (own && lane == 0) aliveM[wv & 7] = am;
      }
      __syncthreads();                                        // S1

      int na = 0;
      #pragma unroll
      for (int g = 0; g < 8; ++g) na += (int)__popcll(aliveM[g]);
      if (na == 0) continue;

      // 2. compaction from registers (order-preserving)
      if (alive) {
        int cg2 = cc >> 6;
        int pre = 0;
        #pragma unroll
        for (int g = 0; g < 8; ++g) if (g < cg2) pre += (int)__popcll(aliveM[g]);
        pre += (int)__popcll(aliveM[cg2] & ((1ull << (cc & 63)) - 1ull));
        cbox2[pre] = mybx[m];
        carea2[pre] = myar[m];
      }
      __syncthreads();                                        // S2

      // 3. dense suppression triangle on compacted set (2-seg depth split)
      {
        int i = c512;
        if (i < na) {
          int ngi = (i >> 6) + 1;
          int gA = seg ? (ngi >> 1) : 0;
          int gB = seg ? ngi : (ngi >> 1);
          if (gA < gB) {
            float4 vi = cbox2[i];
            float ai = carea2[i];
            for (int g = gA; g < gB; ++g) {
              int jmax = i - (g << 6);
              if (jmax > 64) jmax = 64;
              u64 r = 0;
              #pragma unroll 4
              for (int j = 0; j < jmax; ++j) {
                if (sup_test4(vi, ai, cbox2[(g << 6) + j], carea2[(g << 6) + j]))
                  r |= 1ull << j;
              }
              sup[i][g] = r;
            }
          }
        }
      }
      __syncthreads();                                        // S3

      // 4. greedy resolve by wave 0: register rows + next-stage prefetch
      if (tid < 64) {
        u64 kw[8];
        int nst = (na + 63) >> 6;
        u64 srow[8];
        {
          const u64* rp = sup[lane];
          #pragma unroll
          for (int g = 0; g < 8; ++g) srow[g] = rp[g];
        }
        #pragma unroll
        for (int s = 0; s < 8; ++s) {
          u64 nsr[8];
          bool pf = (s + 1 < nst);
          if (pf) {
            const u64* rp = sup[(s + 1) * 64 + lane];
            #pragma unroll
            for (int g = 0; g < 8; ++g) nsr[g] = rp[g];
          }
          u64 kg = 0;
          if (s < nst) {
            int cc2 = s * 64 + lane;
            bool a = (cc2 < na);
            u64 blocked = 0;
            #pragma unroll
            for (int g = 0; g < 8; ++g) if (g < s) blocked |= (srow[g] & kw[g]);
            a = a && (blocked == 0ull);
            u64 r = a ? srow[s] : 0ull;
            u64 cm = __ballot(a);
            while (cm) {
              int j = __builtin_ctzll(cm);
              kg |= 1ull << j;
              u64 rem = __ballot((r >> j) & 1ull);
              cm &= ~(rem | (1ull << j));
            }
          }
          kw[s] = kg;
          if (pf) {
            #pragma unroll
            for (int g = 0; g < 8; ++g) srow[g] = nsr[g];
          }
        }
        if (lane == 0) {
          #pragma unroll
          for (int s = 0; s < 8; ++s) kgW[s] = kw[s];
        }
      }
      __syncthreads();                                        // S4

      // 5. append kept boxes + update s_nk
      if (tid < na) {
        int s = tid >> 6;
        u64 kgw = kgW[s];
        bool kept = (kgw >> (tid & 63)) & 1;
        int pre = 0;
        #pragma unroll
        for (int g = 0; g < 8; ++g) if (g < s) pre += (int)__popcll(kgW[g]);
        pre += (int)__popcll(kgw & ((1ull << (tid & 63)) - 1ull));
        int rank = nk0 + pre;
        if (kept && rank < POST_N) {
          float4 ww = cbox2[tid];
          kbox[rank] = ww; karea[rank] = carea2[tid];
          ob[rank*5+0] = (float)b;
          ob[rank*5+1] = ww.x; ob[rank*5+2] = ww.y; ob[rank*5+3] = ww.z; ob[rank*5+4] = ww.w;
        }
      }
      if (tid == 0) {
        int tot = 0;
        #pragma unroll
        for (int s = 0; s < 8; ++s) tot += (int)__popcll(kgW[s]);
        int nn = nk0 + tot;
        s_nk = nn < POST_N ? nn : POST_N;
      }
      __syncthreads();                                        // S5

      // 6. forward-suppression: new kept boxes kill future register
      //    candidates in parallel (all 1024 threads, static m2 indices)
      int nk1 = s_nk;
      if (nk1 >= POST_N) { done = true; continue; }
      if (nk1 > nk0) {
        #pragma unroll
        for (int m2 = m; m2 < 6; ++m2) {
          bool fut = (m2 > m) || ((tid >> 9) > par);
          if (fut && !((deadm >> m2) & 1)) {
            for (int k = nk0; k < nk1; ++k) {
              if (sup_test4(mybx[m2], myar[m2], kbox[k], karea[k])) {
                deadm |= (1 << m2);
                break;
              }
            }
          }
        }
      }
    }
  }
  __syncthreads();
  int nk = s_nk;
  for (int r = nk + tid; r < POST_N; r += 1024) {
    ob[r*5+0] = (float)b;
    ob[r*5+1] = 0.f; ob[r*5+2] = 0.f; ob[r*5+3] = 0.f; ob[r*5+4] = 0.f;
  }
}

// PROBE: 8x repetition of the exact sort sequence (bitonic is data-oblivious,
// so each rep executes the identical instruction trace). 1 block, image 0.
// Writes checksum to dead scratch (keys region) to prevent DCE. Runs AFTER
// k_final6 — output already produced; probe touches only dead workspace.
// Readout: S_sort ≈ (dur_probe - ~5us load) / 8. Only visible in top-5 if
// dur_probe > k_final6 (~133us), i.e. S > 16us — absence is also a result.
__global__ __launch_bounds__(1024) void k_probe_sort(const u64* __restrict__ cand,
    const unsigned* __restrict__ cnt, unsigned* __restrict__ sink) {
  __shared__ u64 sm[CAND_CAP];   // 64 KiB
  int tid = threadIdx.x;
  unsigned effcnt = cnt[0];
  if (effcnt > CAND_CAP) effcnt = CAND_CAP;
  int e0 = tid << 3;
  u64 v[8];
  #pragma unroll
  for (int r = 0; r < 8; ++r)
    v[r] = ((unsigned)(e0 + r) < effcnt) ? cand[e0 + r] : 0ull;
  for (int rep = 0; rep < 8; ++rep) {
    for (int k = 2; k <= 8; k <<= 1)
      for (int j = k >> 1; j >= 1; j >>= 1) reg_step(v, tid, k, j);
    for (int k = 16; k <= CAND_CAP; k <<= 1) {
      int j = k >> 1;
      for (; j >= 512; j >>= 1) lds_step(sm, v, tid, k, j);
      for (; j >= 8;   j >>= 1) shfl_step(v, tid, k, j);
      for (; j >= 1;   j >>= 1) reg_step(v, tid, k, j);
    }
    __syncthreads();
  }
  u64 acc = 0;
  #pragma unroll
  for (int r = 0; r < 8; ++r) acc ^= v[r];
  sink[tid] = (unsigned)acc ^ (unsigned)(acc >> 32);
}

extern "C" void kernel_launch(void* const* d_in, const int* in_sizes, int n_in,
                              void* d_out, int out_size, void* d_ws, size_t ws_size,
                              hipStream_t stream) {
  const float* cls  = (const float*)d_in[0];   // (32, 18, 128, 128)
  const float* dl   = (const float*)d_in[1];   // (32, 36, 128, 128)
  const float* info = (const float*)d_in[2];   // (32, 3)
  float* out = (float*)d_out;                  // (32, 300, 5)
  char* ws = (char*)d_ws;

  // workspace layout (bytes)
  const size_t OFF_KEYS = 0;                        // 32*147456*4 = 18,874,368
  const size_t OFF_H1   = 18874368;                 // 32*4096*4   =    524,288
  const size_t OFF_H2   = 19398656;                 // 32*4096*4   =    524,288
  const size_t OFF_CNT  = 19922944;                 // 32*64*4     =      8,192
  const size_t OFF_CAND = 19931136;                 // 32*8192*8   =  2,097,152
  const size_t OFF_BOX  = 22028288;                 // 32*8192*16  =  4,194,304
  const size_t WS_NEED  = 26222592;
  if (ws_size < WS_NEED) return;

  unsigned* keys  = (unsigned*)(ws + OFF_KEYS);
  unsigned* h1    = (unsigned*)(ws + OFF_H1);
  unsigned* h2    = (unsigned*)(ws + OFF_H2);
  unsigned* cnt   = (unsigned*)(ws + OFF_CNT);
  u64* cand = (u64*)(ws + OFF_CAND);
  float4* boxes = (float4*)(ws + OFF_BOX);

  // zero h1 + h2 + cnt (cand masked by cnt in k_final6)
  hipMemsetAsync(ws + OFF_H1, 0, OFF_CAND - OFF_H1, stream);

  dim3 g1(HW / 1024, NB);                 // (16, 32)
  k_keys<<<g1, 256, 0, stream>>>(cls, dl, info, keys, h1);
  dim3 gh(8, NB);
  k_hist2<<<gh, 256, 0, stream>>>(keys, h1, h2);
  dim3 gg(GX_GATHER, NB);
  k_gather<<<gg, 256, 0, stream>>>(keys, h1, h2, dl, info, cnt, cand, boxes);
  k_final6<<<NB, 1024, 0, stream>>>(cand, cnt, boxes, out);
  // instrumentation: sort-phase timing probe (writes only dead scratch)
  k_probe_sort<<<1, 1024, 0, stream>>>(cand, cnt, keys);
}

// Round 11
// 315.345 us; speedup vs baseline: 2.4943x; 2.4943x over previous
//
#include <hip/hip_runtime.h>
#include <cstdint>
#include <cstddef>

#pragma clang fp contract(off)

typedef unsigned long long u64;

#define NB 32
#define NA 9
#define NH 128
#define NW 128
#define HW (NH*NW)            // 16384
#define NANCH (NA*HW)         // 147456
#define PRE_N 6000
#define POST_N 300
#define CAND_CAP 8192
#define NMS_T 0.7f
#define GX_GATHER 24          // blocks per image in k_gather
#define NBOX 6144             // boxes carried into NMS
#define CH 512                // NMS chunk size

// Base anchor widths/heights (generate_anchors(16,[.5,1,2],[8,16,32])).
__constant__ float c_wa[9] = {184.f,368.f,736.f,128.f,256.f,512.f,88.f,176.f,352.f};
__constant__ float c_ha[9] = {96.f,192.f,384.f,128.f,256.f,512.f,176.f,352.f,704.f};

__device__ __forceinline__ float4 decode_clip(int a, int h, int w,
    float dx, float dy, float dlw, float dlh, float imh, float imw) {
  float wa = c_wa[a], ha = c_ha[a];
  float cx = (float)w * 16.0f + 8.0f;
  float cy = (float)h * 16.0f + 8.0f;
  float pcx = dx * wa + cx;
  float pcy = dy * ha + cy;
  float pw = expf(dlw) * wa;
  float ph = expf(dlh) * ha;
  float x1 = pcx - 0.5f * pw;
  float y1 = pcy - 0.5f * ph;
  float x2 = pcx + 0.5f * pw;
  float y2 = pcy + 0.5f * ph;
  float4 r;
  r.x = fminf(fmaxf(x1, 0.0f), imw - 1.0f);
  r.y = fminf(fmaxf(y1, 0.0f), imh - 1.0f);
  r.z = fminf(fmaxf(x2, 0.0f), imw - 1.0f);
  r.w = fminf(fmaxf(y2, 0.0f), imh - 1.0f);
  return r;
}

__device__ __forceinline__ unsigned score_key(float sc, float bw, float bh, float msz) {
  unsigned bits = __float_as_uint(sc);
  unsigned key = (bits & 0x80000000u) ? ~bits : (bits | 0x80000000u);
  if (!(bw >= msz && bh >= msz)) key = 0u;   // filtered == score NEG_INF
  return key;
}

__device__ __forceinline__ bool sup_test4(float4 v, float ar, float4 p, float pa) {
  float xx1 = fmaxf(p.x, v.x), yy1 = fmaxf(p.y, v.y);
  float xx2 = fminf(p.z, v.z), yy2 = fminf(p.w, v.w);
  float iw = fmaxf(xx2 - xx1 + 1.0f, 0.0f);
  float ih = fmaxf(yy2 - yy1 + 1.0f, 0.0f);
  float inter = iw * ih;
  float iou = inter / fmaxf(pa + ar - inter, 1e-6f);
  return iou > NMS_T;
}

// ---- hybrid bitonic helpers, 8 elems/thread (k_final merge) ----------------
__device__ __forceinline__ u64 shfl_xor_u64(u64 x, int m) {
  int lo = __shfl_xor((int)(unsigned)x, m, 64);
  int hi = __shfl_xor((int)(unsigned)(x >> 32), m, 64);
  return ((u64)(unsigned)hi << 32) | (unsigned)lo;
}

__device__ __forceinline__ void reg_step(u64 v[8], int t, int k, int j) {
  #pragma unroll
  for (int r = 0; r < 8; ++r) {
    if ((r & j) == 0) {
      int e = (t << 3) + r;
      bool up = ((e & k) == 0);          // up-region = descending
      u64 x = v[r], y = v[r | j];
      u64 mx = x > y ? x : y, mn = x > y ? y : x;
      v[r]     = up ? mx : mn;
      v[r | j] = up ? mn : mx;
    }
  }
}

__device__ __forceinline__ void shfl_step(u64 v[8], int t, int k, int j) {
  int m = j >> 3;
  bool lower = ((t & m) == 0);
  #pragma unroll
  for (int r = 0; r < 8; ++r) {
    int e = (t << 3) + r;
    bool up = ((e & k) == 0);
    u64 pv = shfl_xor_u64(v[r], m);
    bool keepmax = (up == lower);
    u64 x = v[r];
    u64 mx = x > pv ? x : pv, mn = x > pv ? pv : x;
    v[r] = keepmax ? mx : mn;
  }
}

// j >= 512: cross-wave exchange via LDS, swizzled slot(e) = (e&7)*1024+(e>>3).
__device__ __forceinline__ void lds_step(u64* sm, u64 v[8], int t, int k, int j) {
  int m = j >> 3;
  __syncthreads();
  #pragma unroll
  for (int r = 0; r < 8; ++r) sm[(r << 10) | t] = v[r];
  __syncthreads();
  bool lower = ((t & m) == 0);
  bool up = (((t << 3) & k) == 0);
  bool keepmax = (up == lower);
  int pt = t ^ m;
  #pragma unroll
  for (int r = 0; r < 8; ++r) {
    u64 pv = sm[(r << 10) | pt];
    u64 x = v[r];
    u64 mx = x > pv ? x : pv, mn = x > pv ? pv : x;
    v[r] = keepmax ? mx : mn;
  }
}

// ---- presort helpers, 4 elems/thread, direction flag (flip=true => asc) ----
__device__ __forceinline__ void p_reg(u64 v[4], int t, int k, int j, bool flip) {
  #pragma unroll
  for (int r = 0; r < 4; ++r) {
    if ((r & j) == 0) {
      int e = (t << 2) + r;
      bool up = (((e & k) == 0) != flip);
      u64 x = v[r], y = v[r | j];
      u64 mx = x > y ? x : y, mn = x > y ? y : x;
      v[r]     = up ? mx : mn;
      v[r | j] = up ? mn : mx;
    }
  }
}

__device__ __forceinline__ void p_shfl(u64 v[4], int t, int k, int j, bool flip) {
  int m = j >> 2;                         // 1..32 for j in {4..128}
  bool lower = ((t & m) == 0);
  #pragma unroll
  for (int r = 0; r < 4; ++r) {
    int e = (t << 2) + r;
    bool up = (((e & k) == 0) != flip);
    u64 pv = shfl_xor_u64(v[r], m);
    bool keepmax = (up == lower);
    u64 x = v[r];
    u64 mx = x > pv ? x : pv, mn = x > pv ? pv : x;
    v[r] = keepmax ? mx : mn;
  }
}

// j >= 256 (m >= 64): cross-wave via LDS; slot(e) = (e&3)*512 + (e>>2).
__device__ __forceinline__ void p_lds(u64* sm, u64 v[4], int t, int k, int j, bool flip) {
  int m = j >> 2;
  __syncthreads();
  #pragma unroll
  for (int r = 0; r < 4; ++r) sm[(r << 9) | t] = v[r];
  __syncthreads();
  bool lower = ((t & m) == 0);
  bool up = ((((t << 2) & k) == 0) != flip);   // k >= 512: r-bits irrelevant
  bool keepmax = (up == lower);
  int pt = t ^ m;
  #pragma unroll
  for (int r = 0; r < 4; ++r) {
    u64 pv = sm[(r << 9) | pt];
    u64 x = v[r];
    u64 mx = x > pv ? x : pv, mn = x > pv ? pv : x;
    v[r] = keepmax ? mx : mn;
  }
}

// ---- inline radix-select helpers (256-thread blocks; r5-verified) ----------
__device__ void find_B(const unsigned* __restrict__ hb, unsigned* part,
                       unsigned* outB, unsigned* outCum) {
  int tid = threadIdx.x;
  unsigned s = 0;
  for (int i = 0; i < 16; ++i) s += hb[tid*16 + i];
  part[tid] = s;
  __syncthreads();
  for (int off = 1; off < 256; off <<= 1) {
    unsigned v = (tid + off < 256) ? part[tid + off] : 0u;
    __syncthreads();
    part[tid] += v;
    __syncthreads();
  }
  unsigned St = part[tid];
  unsigned Sn = (tid < 255) ? part[tid + 1] : 0u;
  if (St >= (unsigned)PRE_N && Sn < (unsigned)PRE_N) {
    unsigned cum = Sn, B = 0, cumAbove = Sn;
    for (int i = 15; i >= 0; --i) {
      unsigned v = hb[tid*16 + i];
      if (cum + v >= (unsigned)PRE_N) { B = (unsigned)(tid*16 + i); cumAbove = cum; break; }
      cum += v;
    }
    *outB = B; *outCum = cumAbove;
  }
  __syncthreads();
}

__device__ void find_thr(const unsigned* __restrict__ hb2, unsigned B, unsigned cum0,
                         unsigned* part, unsigned* outThr) {
  int tid = threadIdx.x;
  unsigned s = 0;
  for (int i = 0; i < 16; ++i) s += hb2[tid*16 + i];
  part[tid] = s;
  __syncthreads();
  for (int off = 1; off < 256; off <<= 1) {
    unsigned v = (tid + off < 256) ? part[tid + off] : 0u;
    __syncthreads();
    part[tid] += v;
    __syncthreads();
  }
  unsigned St = cum0 + part[tid];
  unsigned Sn = cum0 + ((tid < 255) ? part[tid + 1] : 0u);
  if (St >= (unsigned)PRE_N && Sn < (unsigned)PRE_N) {
    unsigned cum = Sn, t = 1u;
    for (int i = 15; i >= 0; --i) {
      unsigned v = hb2[tid*16 + i];
      if (cum + v >= (unsigned)PRE_N) {
        t = (B << 20) | ((unsigned)(tid*16 + i) << 8);
        break;
      }
      cum += v;
    }
    if (t == 0u) t = 1u;
    *outThr = t;
  }
  __syncthreads();
}

// K1: decode+filter -> order-preserving uint key per anchor, fused coarse
// histogram (key>>20, 4096 bins) aggregated in LDS, flushed per block.
__global__ __launch_bounds__(256) void k_keys(const float* __restrict__ cls,
    const float* __restrict__ dl, const float* __restrict__ info,
    unsigned* __restrict__ keys, unsigned* __restrict__ hist) {
  __shared__ unsigned hsh[4096];
  int tid = threadIdx.x;
  for (int i = tid; i < 4096; i += 256) hsh[i] = 0;
  int t = blockIdx.x * 256 + tid;            // 0..4095
  int b = blockIdx.y;
  int hw0 = t * 4;                           // 4 consecutive hw, same row
  int h = hw0 >> 7;
  const float* dlb  = dl  + (size_t)b * (4*NA*HW);
  const float* clsb = cls + (size_t)b * (2*NA*HW);
  float imh = info[b*3+0], imw = info[b*3+1];
  float msz = 16.0f * info[b*3+2];
  unsigned* kb = keys + (size_t)b * NANCH;
  __syncthreads();
  #pragma unroll
  for (int a = 0; a < 9; ++a) {
    float4 dx4 = *(const float4*)&dlb[(a*4+0)*HW + hw0];
    float4 dy4 = *(const float4*)&dlb[(a*4+1)*HW + hw0];
    float4 dw4 = *(const float4*)&dlb[(a*4+2)*HW + hw0];
    float4 dh4 = *(const float4*)&dlb[(a*4+3)*HW + hw0];
    float4 sc4 = *(const float4*)&clsb[(NA+a)*HW + hw0];
    uint4 out;
    {
      float4 bx = decode_clip(a, h, (hw0+0)&127, dx4.x, dy4.x, dw4.x, dh4.x, imh, imw);
      out.x = score_key(sc4.x, bx.z-bx.x+1.0f, bx.w-bx.y+1.0f, msz);
    }
    {
      float4 bx = decode_clip(a, h, (hw0+1)&127, dx4.y, dy4.y, dw4.y, dh4.y, imh, imw);
      out.y = score_key(sc4.y, bx.z-bx.x+1.0f, bx.w-bx.y+1.0f, msz);
    }
    {
      float4 bx = decode_clip(a, h, (hw0+2)&127, dx4.z, dy4.z, dw4.z, dh4.z, imh, imw);
      out.z = score_key(sc4.z, bx.z-bx.x+1.0f, bx.w-bx.y+1.0f, msz);
    }
    {
      float4 bx = decode_clip(a, h, (hw0+3)&127, dx4.w, dy4.w, dw4.w, dh4.w, imh, imw);
      out.w = score_key(sc4.w, bx.z-bx.x+1.0f, bx.w-bx.y+1.0f, msz);
    }
    *(uint4*)&kb[a*HW + hw0] = out;
    atomicAdd(&hsh[out.x >> 20], 1u);
    atomicAdd(&hsh[out.y >> 20], 1u);
    atomicAdd(&hsh[out.z >> 20], 1u);
    atomicAdd(&hsh[out.w >> 20], 1u);
  }
  __syncthreads();
  unsigned* gb = hist + ((size_t)b << 12);
  for (int i = tid; i < 4096; i += 256) {
    unsigned v = hsh[i];
    if (v) atomicAdd(&gb[i], v);
  }
}

// K2: refine histogram — bits[19:8] of keys whose top-12 == B (B inline from h1).
__global__ __launch_bounds__(256) void k_hist2(const unsigned* __restrict__ keys,
    const unsigned* __restrict__ hist1, unsigned* __restrict__ hist2) {
  __shared__ unsigned h[4096];
  __shared__ unsigned part[256];
  __shared__ unsigned sB, sCum;
  int b = blockIdx.y, tid = threadIdx.x;
  for (int i = tid; i < 4096; i += 256) h[i] = 0;
  __syncthreads();
  find_B(hist1 + ((size_t)b << 12), part, &sB, &sCum);
  unsigned B = sB;
  const unsigned* kb = keys + (size_t)b * NANCH;
  for (int i = blockIdx.x * 256 + tid; i < NANCH; i += gridDim.x * 256) {
    unsigned k = kb[i];
    if ((k >> 20) == B) atomicAdd(&h[(k >> 8) & 4095u], 1u);
  }
  __syncthreads();
  unsigned* gb = hist2 + ((size_t)b << 12);
  for (int i = tid; i < 4096; i += 256) { unsigned v = h[i]; if (v) atomicAdd(&gb[i], v); }
}

// K3: gather (key,[~oi:18|pos:13]) for key >= thr, AND decode the box into
// boxes[b][pos]. Tie-break preserved (~oi); pos lets the final kernel fetch
// the box without touching dl.
__global__ __launch_bounds__(256) void k_gather(const unsigned* __restrict__ keys,
    const unsigned* __restrict__ hist1, const unsigned* __restrict__ hist2,
    const float* __restrict__ dl, const float* __restrict__ info,
    unsigned* __restrict__ cnt, u64* __restrict__ cand,
    float4* __restrict__ boxes) {
  int b = blockIdx.y, tid = threadIdx.x;
  int lane = tid & 63, wv = tid >> 6;
  __shared__ unsigned part[256];
  __shared__ unsigned sB, sCum, sThr;
  __shared__ unsigned wcnt[4], woff[4], blkbase;
  if (tid == 0) sThr = 1u;
  __syncthreads();
  find_B(hist1 + ((size_t)b << 12), part, &sB, &sCum);
  find_thr(hist2 + ((size_t)b << 12), sB, sCum, part, &sThr);
  unsigned t_ = sThr;
  const unsigned* kb = keys + (size_t)b * NANCH;
  const float* dlb = dl + (size_t)b * (4*NA*HW);
  float imh = info[b*3+0], imw = info[b*3+1];
  u64* cb = cand + (size_t)b * CAND_CAP;
  float4* bxc = boxes + (size_t)b * CAND_CAP;
  unsigned* cp = cnt + (size_t)b * 64;
  const int PER_BLK = NANCH / GX_GATHER;      // 6144
  int base0 = blockIdx.x * PER_BLK;
  for (int it = 0; it < PER_BLK / 256; ++it) {
    int j = base0 + it * 256 + tid;
    unsigned key = kb[j];
    bool pass = key >= t_;
    u64 mask = __ballot(pass);
    if (lane == 0) wcnt[wv] = (unsigned)__popcll(mask);
    __syncthreads();
    if (tid == 0) {
      unsigned s0 = 0;
      for (int w = 0; w < 4; ++w) { woff[w] = s0; s0 += wcnt[w]; }
      blkbase = s0 ? atomicAdd(cp, s0) : 0u;
    }
    __syncthreads();
    if (pass) {
      unsigned pos = blkbase + woff[wv] + (unsigned)__popcll(mask & ((1ull << lane) - 1ull));
      if (pos < CAND_CAP) {
        int a = j >> 14, hw = j & (HW - 1);
        unsigned oi = (unsigned)(hw * 9 + a);
        unsigned noi = (~oi) & 0x3FFFFu;          // 18-bit inverted index
        cb[pos] = ((u64)key << 32) | ((u64)noi << 13) | (u64)pos;
        bxc[pos] = decode_clip(a, hw >> 7, hw & 127,
                               dlb[(a*4+0)*HW + hw], dlb[(a*4+1)*HW + hw],
                               dlb[(a*4+2)*HW + hw], dlb[(a*4+3)*HW + hw],
                               imh, imw);
      }
    }
    __syncthreads();
  }
}

// K4: presort — each block fully sorts one 2048-run of cand, direction
// alternating desc/asc by run parity (= the state the full 8192 bitonic has
// after level k=2048, per up=((e&k)==0) convention). 128 blocks x 512 thr,
// 4 elems/thread; masks unwritten slots to 0 via cnt. Takes 66 of the 91
// sort steps off the 32-CU critical path (probe r10: sort = ~58us of 133).
__global__ __launch_bounds__(512) void k_presort(u64* __restrict__ cand,
                                                 const unsigned* __restrict__ cnt) {
  __shared__ u64 sm[2048];   // 16 KiB
  int blk = blockIdx.x;
  int b = blk >> 2, q = blk & 3;
  bool flip = (q & 1) != 0;                  // odd run => ascending
  unsigned effcnt = cnt[b * 64];
  if (effcnt > CAND_CAP) effcnt = CAND_CAP;
  u64* cb = cand + (size_t)b * CAND_CAP + (size_t)q * 2048;
  int base = q * 2048;
  int t = threadIdx.x;
  int e0 = t << 2;
  u64 v[4];
  #pragma unroll
  for (int r = 0; r < 4; ++r)
    v[r] = ((unsigned)(base + e0 + r) < effcnt) ? cb[e0 + r] : 0ull;
  for (int k = 2; k <= 2048; k <<= 1) {
    int j = k >> 1;
    for (; j >= 256; j >>= 1) p_lds(sm, v, t, k, j, flip);
    for (; j >= 4;   j >>= 1) p_shfl(v, t, k, j, flip);
    for (; j >= 1;   j >>= 1) p_reg(v, t, k, j, flip);
  }
  #pragma unroll
  for (int r = 0; r < 4; ++r) cb[e0 + r] = v[r];
}

// K5: final merge (k=4096,8192 only: 25 steps vs 91) + box gather + greedy
// NMS with forward suppression (r9-verified, unchanged).
__global__ __launch_bounds__(1024) void k_final7(const u64* __restrict__ cand,
    const float4* __restrict__ boxes, float* __restrict__ out) {
  __shared__ float4 bx[NBOX];        // 96 KiB; first 64 KiB aliased as u64 sm[8192]
  __shared__ float4 cbox2[CH];       // compacted alive boxes (score order)
  __shared__ float  carea2[CH];
  __shared__ float4 kbox[POST_N];
  __shared__ float  karea[POST_N];
  __shared__ u64 sup[CH][9];         // padded row
  __shared__ u64 aliveM[8];
  __shared__ u64 kgW[8];
  __shared__ int s_nk;
  u64* sm = (u64*)bx;

  int b = blockIdx.x, tid = threadIdx.x;
  int lane = tid & 63, wv = tid >> 6;
  if (tid == 0) s_nk = 0;

  // ---- load 8 consecutive candidates (all slots initialized by presort) ----
  const u64* cb = cand + (size_t)b * CAND_CAP;
  int e0 = tid << 3;
  u64 v[8];
  #pragma unroll
  for (int r = 0; r < 8; ++r) v[r] = cb[e0 + r];

  // ---- merge the 4 presorted runs: levels k=4096 and k=8192 only ----
  for (int k = 4096; k <= CAND_CAP; k <<= 1) {
    int j = k >> 1;
    for (; j >= 512; j >>= 1) lds_step(sm, v, tid, k, j);
    for (; j >= 8;   j >>= 1) shfl_step(v, tid, k, j);
    for (; j >= 1;   j >>= 1) reg_step(v, tid, k, j);
  }
  __syncthreads();   // lds_step reads done before bx overwrites sm bytes

  // ---- fill bx by rank from the boxes array ----
  const float4* bxc = boxes + (size_t)b * CAND_CAP;
  #pragma unroll
  for (int r = 0; r < 8; ++r) {
    int rank = e0 + r;
    if (rank < NBOX) {
      u64 ck = (rank < PRE_N) ? v[r] : 0ull;
      float4 w = make_float4(0.f, 0.f, -1.f, -1.f);   // invalid: width 0
      if ((unsigned)(ck >> 32) != 0u)
        w = bxc[(unsigned)(ck & 0x1FFFu)];
      bx[rank] = w;
    }
  }
  __syncthreads();

  // ---- reload strided: thread t owns ranks t+1024*m (m static) ----
  float4 mybx[6];
  float  myar[6];
  int deadm = 0;
  #pragma unroll
  for (int m = 0; m < 6; ++m) {
    float4 w = bx[tid + (m << 10)];
    mybx[m] = w;
    float wid = w.z - w.x + 1.0f;
    myar[m] = wid * (w.w - w.y + 1.0f);
    if (!(wid > 0.0f)) deadm |= (1 << m);
  }

  // ---- greedy NMS, 12 chunks fully unrolled (chunk c=2m+par) ----
  float* ob = out + (size_t)b * (POST_N * 5);
  int c512 = tid & (CH - 1);
  int seg = tid >> 9;
  bool done = false;

  #pragma unroll
  for (int m = 0; m < 6; ++m) {
    #pragma unroll
    for (int par = 0; par < 2; ++par) {
      if (done) continue;
      int nk0 = s_nk;

      // 1. alive ballot straight from register flags (owner waves = 8)
      bool own = (tid >> 9) == par;
      int cc = tid - (par << 9);
      bool alive = own && !((deadm >> m) & 1);
      {
        u64 am = __ballot(alive);
        if (own && lane == 0) aliveM[wv & 7] = am;
      }
      __syncthreads();                                        // S1

      int na = 0;
      #pragma unroll
      for (int g = 0; g < 8; ++g) na += (int)__popcll(aliveM[g]);
      if (na == 0) continue;

      // 2. compaction from registers (order-preserving)
      if (alive) {
        int cg2 = cc >> 6;
        int pre = 0;
        #pragma unroll
        for (int g = 0; g < 8; ++g) if (g < cg2) pre += (int)__popcll(aliveM[g]);
        pre += (int)__popcll(aliveM[cg2] & ((1ull << (cc & 63)) - 1ull));
        cbox2[pre] = mybx[m];
        carea2[pre] = myar[m];
      }
      __syncthreads();                                        // S2

      // 3. dense suppression triangle on compacted set (2-seg depth split)
      {
        int i = c512;
        if (i < na) {
          int ngi = (i >> 6) + 1;
          int gA = seg ? (ngi >> 1) : 0;
          int gB = seg ? ngi : (ngi >> 1);
          if (gA < gB) {
            float4 vi = cbox2[i];
            float ai = carea2[i];
            for (int g = gA; g < gB; ++g) {
              int jmax = i - (g << 6);
              if (jmax > 64) jmax = 64;
              u64 r = 0;
              #pragma unroll 4
              for (int j = 0; j < jmax; ++j) {
                if (sup_test4(vi, ai, cbox2[(g << 6) + j], carea2[(g << 6) + j]))
                  r |= 1ull << j;
              }
              sup[i][g] = r;
            }
          }
        }
      }
      __syncthreads();                                        // S3

      // 4. greedy resolve by wave 0: register rows + next-stage prefetch
      if (tid < 64) {
        u64 kw[8];
        int nst = (na + 63) >> 6;
        u64 srow[8];
        {
          const u64* rp = sup[lane];
          #pragma unroll
          for (int g = 0; g < 8; ++g) srow[g] = rp[g];
        }
        #pragma unroll
        for (int s = 0; s < 8; ++s) {
          u64 nsr[8];
          bool pf = (s + 1 < nst);
          if (pf) {
            const u64* rp = sup[(s + 1) * 64 + lane];
            #pragma unroll
            for (int g = 0; g < 8; ++g) nsr[g] = rp[g];
          }
          u64 kg = 0;
          if (s < nst) {
            int cc2 = s * 64 + lane;
            bool a = (cc2 < na);
            u64 blocked = 0;
            #pragma unroll
            for (int g = 0; g < 8; ++g) if (g < s) blocked |= (srow[g] & kw[g]);
            a = a && (blocked == 0ull);
            u64 r = a ? srow[s] : 0ull;
            u64 cm = __ballot(a);
            while (cm) {
              int j = __builtin_ctzll(cm);
              kg |= 1ull << j;
              u64 rem = __ballot((r >> j) & 1ull);
              cm &= ~(rem | (1ull << j));
            }
          }
          kw[s] = kg;
          if (pf) {
            #pragma unroll
            for (int g = 0; g < 8; ++g) srow[g] = nsr[g];
          }
        }
        if (lane == 0) {
          #pragma unroll
          for (int s = 0; s < 8; ++s) kgW[s] = kw[s];
        }
      }
      __syncthreads();                                        // S4

      // 5. append kept boxes + update s_nk
      if (tid < na) {
        int s = tid >> 6;
        u64 kgw = kgW[s];
        bool kept = (kgw >> (tid & 63)) & 1;
        int pre = 0;
        #pragma unroll
        for (int g = 0; g < 8; ++g) if (g < s) pre += (int)__popcll(kgW[g]);
        pre += (int)__popcll(kgw & ((1ull << (tid & 63)) - 1ull));
        int rank = nk0 + pre;
        if (kept && rank < POST_N) {
          float4 ww = cbox2[tid];
          kbox[rank] = ww; karea[rank] = carea2[tid];
          ob[rank*5+0] = (float)b;
          ob[rank*5+1] = ww.x; ob[rank*5+2] = ww.y; ob[rank*5+3] = ww.z; ob[rank*5+4] = ww.w;
        }
      }
      if (tid == 0) {
        int tot = 0;
        #pragma unroll
        for (int s = 0; s < 8; ++s) tot += (int)__popcll(kgW[s]);
        int nn = nk0 + tot;
        s_nk = nn < POST_N ? nn : POST_N;
      }
      __syncthreads();                                        // S5

      // 6. forward-suppression: new kept boxes kill future register
      //    candidates in parallel (all 1024 threads, static m2 indices)
      int nk1 = s_nk;
      if (nk1 >= POST_N) { done = true; continue; }
      if (nk1 > nk0) {
        #pragma unroll
        for (int m2 = m; m2 < 6; ++m2) {
          bool fut = (m2 > m) || ((tid >> 9) > par);
          if (fut && !((deadm >> m2) & 1)) {
            for (int k = nk0; k < nk1; ++k) {
              if (sup_test4(mybx[m2], myar[m2], kbox[k], karea[k])) {
                deadm |= (1 << m2);
                break;
              }
            }
          }
        }
      }
    }
  }
  __syncthreads();
  int nk = s_nk;
  for (int r = nk + tid; r < POST_N; r += 1024) {
    ob[r*5+0] = (float)b;
    ob[r*5+1] = 0.f; ob[r*5+2] = 0.f; ob[r*5+3] = 0.f; ob[r*5+4] = 0.f;
  }
}

extern "C" void kernel_launch(void* const* d_in, const int* in_sizes, int n_in,
                              void* d_out, int out_size, void* d_ws, size_t ws_size,
                              hipStream_t stream) {
  const float* cls  = (const float*)d_in[0];   // (32, 18, 128, 128)
  const float* dl   = (const float*)d_in[1];   // (32, 36, 128, 128)
  const float* info = (const float*)d_in[2];   // (32, 3)
  float* out = (float*)d_out;                  // (32, 300, 5)
  char* ws = (char*)d_ws;

  // workspace layout (bytes)
  const size_t OFF_KEYS = 0;                        // 32*147456*4 = 18,874,368
  const size_t OFF_H1   = 18874368;                 // 32*4096*4   =    524,288
  const size_t OFF_H2   = 19398656;                 // 32*4096*4   =    524,288
  const size_t OFF_CNT  = 19922944;                 // 32*64*4     =      8,192
  const size_t OFF_CAND = 19931136;                 // 32*8192*8   =  2,097,152
  const size_t OFF_BOX  = 22028288;                 // 32*8192*16  =  4,194,304
  const size_t WS_NEED  = 26222592;
  if (ws_size < WS_NEED) return;

  unsigned* keys  = (unsigned*)(ws + OFF_KEYS);
  unsigned* h1    = (unsigned*)(ws + OFF_H1);
  unsigned* h2    = (unsigned*)(ws + OFF_H2);
  unsigned* cnt   = (unsigned*)(ws + OFF_CNT);
  u64* cand = (u64*)(ws + OFF_CAND);
  float4* boxes = (float4*)(ws + OFF_BOX);

  // zero h1 + h2 + cnt (cand masked by cnt in k_presort)
  hipMemsetAsync(ws + OFF_H1, 0, OFF_CAND - OFF_H1, stream);

  dim3 g1(HW / 1024, NB);                 // (16, 32)
  k_keys<<<g1, 256, 0, stream>>>(cls, dl, info, keys, h1);
  dim3 gh(8, NB);
  k_hist2<<<gh, 256, 0, stream>>>(keys, h1, h2);
  dim3 gg(GX_GATHER, NB);
  k_gather<<<gg, 256, 0, stream>>>(keys, h1, h2, dl, info, cnt, cand, boxes);
  k_presort<<<NB * 4, 512, 0, stream>>>(cand, cnt);
  k_final7<<<NB, 1024, 0, stream>>>(cand, boxes, out);
}